// Round 12
// baseline (9144.570 us; speedup 1.0000x reference)
//
#include <hip/hip_runtime.h>

typedef unsigned short USH;
typedef unsigned int u32;
typedef unsigned long long u64;
typedef float v4f __attribute__((ext_vector_type(4)));
typedef __bf16 v8bf __attribute__((ext_vector_type(8)));
typedef u32 v4u __attribute__((ext_vector_type(4)));

#define B_ 64
#define T_ 512
#define E_ 512
#define H_ 1024
#define GRID 256

__device__ __forceinline__ USH f2b(float x) {
  union { float f; u32 u; } v; v.f = x;
  u32 r = v.u + 0x7FFFu + ((v.u >> 16) & 1u);
  return (USH)(r >> 16);
}
__device__ __forceinline__ v8bf pack8(float4 a, float4 b) {
  union { USH s[8]; v8bf v; } r;
  r.s[0] = f2b(a.x); r.s[1] = f2b(a.y); r.s[2] = f2b(a.z); r.s[3] = f2b(a.w);
  r.s[4] = f2b(b.x); r.s[5] = f2b(b.y); r.s[6] = f2b(b.z); r.s[7] = f2b(b.w);
  return r.v;
}
__device__ __forceinline__ v4f MF(v8bf a, v8bf b, v4f c) {
  return __builtin_amdgcn_mfma_f32_16x16x32_bf16(a, b, c, 0, 0, 0);
}
__device__ __forceinline__ float sigm(float x) { return 1.0f / (1.0f + __expf(-x)); }
__device__ __forceinline__ float tanhx(float x) { return 1.0f - 2.0f / (__expf(2.0f * x) + 1.0f); }

// L3-coherent (bypass L1+L2)
__device__ __forceinline__ v4u ldc16(u64 a) {
  v4u d;
  asm volatile("global_load_dwordx4 %0, %1, off sc0 sc1" : "=v"(d) : "v"(a));
  return d;
}
// L2-path load (bypass L1 only) — fast same-XCD handoff
__device__ __forceinline__ v4u ldl2(u64 a) {
  v4u d;
  asm volatile("global_load_dwordx4 %0, %1, off sc0" : "=v"(d) : "v"(a));
  return d;
}
// plain store -> own-XCD L2 (same-XCD consumers)
__device__ __forceinline__ void stp16(u64 a, v4u d) {
  asm volatile("global_store_dwordx4 %0, %1, off" :: "v"(a), "v"(d) : "memory");
}
// write-through store -> L3 (cross-XCD consumers / correctness fallback)
__device__ __forceinline__ void stc16(u64 a, v4u d) {
  asm volatile("global_store_dwordx4 %0, %1, off sc1" :: "v"(a), "v"(d) : "memory");
}
__device__ __forceinline__ void stdw(u64 a, u32 v) {
  asm volatile("global_store_dword %0, %1, off sc1" :: "v"(a), "v"(v) : "memory");
}

// ---------------- embedding gather (-> bf16) ----------------
__global__ void gatherk(const int* __restrict__ x, const float* __restrict__ emb, USH* __restrict__ xeb) {
  int r = blockIdx.x;
  int id = x[r];
  const float4* e = reinterpret_cast<const float4*>(emb + (long)id * E_);
  float4 v = e[threadIdx.x];
  ushort4 q = make_ushort4(f2b(v.x), f2b(v.y), f2b(v.z), f2b(v.w));
  *reinterpret_cast<ushort4*>(xeb + (long)r * E_ + threadIdx.x * 4) = q;
}

// ---------------- fused persistent kernel (512-thread blocks, role = blk%8) ----------------
// role 0/1  : GRU scan group 0/1 (32 blocks each; cb = blk>>3 -> 32 h-cols). With the
//             %8->XCD round-robin heuristic each group is XCD-resident, so the dual-store
//             (plain->L2, sc1->L3) gives same-XCD consumers ~L2-latency handoff.
//             Correctness never depends on placement: sc1 copy + sentinel-verify +
//             sticky escalation to sc0+sc1 covers every ordering/placement.
// role 2/3  : emissions (2 sub-units of 256 thr; 128 streams).
// role 4    : blk>>3 <8 -> CRF (8 waves = 8 batch rows); blk==68 -> final sum; else exit.
// role 5..7 : exit.
__global__ __launch_bounds__(512, 1) void fused(
    const USH* __restrict__ xeb, const float* __restrict__ wih, const float* __restrict__ whh,
    const float* __restrict__ bih, const float* __restrict__ bhh, char* __restrict__ hsC,
    const float* __restrict__ fcw, const float* __restrict__ fcb,
    float* __restrict__ em, const int* __restrict__ tags, const float* __restrict__ stv,
    const float* __restrict__ env, const float* __restrict__ trn, float* __restrict__ res,
    float* __restrict__ outp)
{
  __shared__ float redS[12288];   // 48KB
  __shared__ USH  trpS[1024];     // 2KB

  const int tid = threadIdx.x;
  const int role = blockIdx.x & 7, idx8 = blockIdx.x >> 3;
  const v4f z4 = {0.f, 0.f, 0.f, 0.f};

  // purge own-XCD L2 of stale lines (prior replay / harness poison) before any sc0 read
  if (tid == 0)
    (void)__hip_atomic_load((const u32*)hsC, __ATOMIC_ACQUIRE, __HIP_MEMORY_SCOPE_AGENT);
  __syncthreads();

  if (role < 2) {
    // ================= scan role =================
    const int wv = tid >> 6, ln = tid & 63;
    const int l16 = ln & 15, lq = ln >> 4;
    const int half = wv >> 2, kq = wv & 3;
    const int bg = role, cb = idx8;
    const int b0 = bg * 32, c0 = cb * 32;

    v8bf wihf[4][3], whhf[8][3];
    #pragma unroll
    for (int kt = 0; kt < 4; ++kt)
      #pragma unroll
      for (int g = 0; g < 3; ++g) {
        const float* wp = wih + (size_t)(g * H_ + c0 + half * 16 + l16) * E_ + kq * 128 + kt * 32 + lq * 8;
        wihf[kt][g] = pack8(*reinterpret_cast<const float4*>(wp),
                            *reinterpret_cast<const float4*>(wp + 4));
      }
    #pragma unroll
    for (int kt = 0; kt < 8; ++kt)
      #pragma unroll
      for (int g = 0; g < 3; ++g) {
        const float* wp = whh + (size_t)(g * H_ + c0 + half * 16 + l16) * H_ + kq * 256 + kt * 32 + lq * 8;
        whhf[kt][g] = pack8(*reinterpret_cast<const float4*>(wp),
                            *reinterpret_cast<const float4*>(wp + 4));
      }

    const int cgl = c0 + half * 16 + l16;
    const float bir = bih[cgl], biz = bih[H_ + cgl], bin = bih[2 * H_ + cgl];
    const float bhr = bhh[cgl], bhz = bhh[H_ + cgl], bhn = bhh[2 * H_ + cgl];

    const USH* a1b = xeb + (size_t)(b0 + l16) * (T_ * E_) + kq * 128 + lq * 8;
    const u64 hC = (u64)(uintptr_t)hsC + (u64)bg * 65536;
    const int lane_off = (lq >> 1) * 1024 + l16 * 32 + (lq & 1) * 16;
    // full writer coverage: 8 source tiles x 4 writer-quarters; lanes duplicated mod 32
    const u64 probe_off = (u64)((kq * 8 + ((ln & 31) >> 2)) * 2048 + (ln & 3) * 512 + 508);

    float hp0 = 0.f, hp1 = 0.f, hp2 = 0.f, hp3 = 0.f;
    v4f* rv = reinterpret_cast<v4f*>(redS);
    const int rbase = half * 1536;

    uint4 pf[8];
    #pragma unroll
    for (int kt = 0; kt < 4; ++kt) {
      pf[kt * 2]     = *reinterpret_cast<const uint4*>(a1b + kt * 32);
      pf[kt * 2 + 1] = *reinterpret_cast<const uint4*>(a1b + 16 * (T_ * E_) + kt * 32);
    }
    u32 pr = 0;
    bool esc = false;   // sticky: placement-wrong waves fall back to L3 probing

    for (int t = 0; t < T_; ++t) {
      v4f acc[8];
      #pragma unroll
      for (int i = 0; i < 8; ++i) acc[i] = z4;

      // ---- phase 1: xe_t @ w_ih^T ----
      #pragma unroll
      for (int kt = 0; kt < 4; ++kt) {
        v8bf a0 = __builtin_bit_cast(v8bf, pf[kt * 2]);
        v8bf a1f = __builtin_bit_cast(v8bf, pf[kt * 2 + 1]);
        acc[0] = MF(a0, wihf[kt][0], acc[0]); acc[1] = MF(a1f, wihf[kt][0], acc[1]);
        acc[2] = MF(a0, wihf[kt][1], acc[2]); acc[3] = MF(a1f, wihf[kt][1], acc[3]);
        acc[4] = MF(a0, wihf[kt][2], acc[4]); acc[5] = MF(a1f, wihf[kt][2], acc[5]);
      }

      if (t > 0) {
        const u64 hbase = hC + (u64)(t - 1) * 131072;
        const u64 pa = hbase + probe_off;
        int rounds = 0;
        // ---- probe (issued at end of previous step) ----
        while (true) {
          asm volatile("s_waitcnt vmcnt(0)" ::: "memory");
          __builtin_amdgcn_sched_barrier(0);
          if (__ballot(pr != 0xFFFFFFFFu) == ~0ull) break;
          if (++rounds >= 4) esc = true;
          if (!esc) asm volatile("global_load_dword %0, %1, off sc0" : "=v"(pr) : "v"(pa));
          else      asm volatile("global_load_dword %0, %1, off sc0 sc1" : "=v"(pr) : "v"(pa));
        }
        // ---- payload: L2-path first, escalate retries to L3 ----
        v4u ha[16];
        #pragma unroll
        for (int kt = 0; kt < 8; ++kt) {
          ha[kt * 2]     = ldl2(hbase + (u64)((kq * 8 + kt) * 2048) + lane_off);
          ha[kt * 2 + 1] = ldl2(hbase + (u64)((kq * 8 + kt) * 2048 + 512) + lane_off);
        }
        asm volatile("s_waitcnt vmcnt(0)" ::: "memory");
        __builtin_amdgcn_sched_barrier(0);
        bool bad = false;
        #pragma unroll
        for (int f = 0; f < 16; ++f) {
          #pragma unroll
          for (int d = 0; d < 4; ++d) bad |= (ha[f][d] == 0xFFFFFFFFu);
        }
        while (__ballot(bad) != 0ull) {
          __builtin_amdgcn_s_sleep(1);
          #pragma unroll
          for (int kt = 0; kt < 8; ++kt) {
            ha[kt * 2]     = ldc16(hbase + (u64)((kq * 8 + kt) * 2048) + lane_off);
            ha[kt * 2 + 1] = ldc16(hbase + (u64)((kq * 8 + kt) * 2048 + 512) + lane_off);
          }
          asm volatile("s_waitcnt vmcnt(0)" ::: "memory");
          __builtin_amdgcn_sched_barrier(0);
          bad = false;
          #pragma unroll
          for (int f = 0; f < 16; ++f) {
            #pragma unroll
            for (int d = 0; d < 4; ++d) bad |= (ha[f][d] == 0xFFFFFFFFu);
          }
        }
        // ---- phase 2: h_{t-1} @ w_hh^T ----
        #pragma unroll
        for (int kt = 0; kt < 8; ++kt) {
          v8bf a0 = __builtin_bit_cast(v8bf, ha[kt * 2]);
          v8bf a1f = __builtin_bit_cast(v8bf, ha[kt * 2 + 1]);
          acc[0] = MF(a0, whhf[kt][0], acc[0]); acc[1] = MF(a1f, whhf[kt][0], acc[1]);
          acc[2] = MF(a0, whhf[kt][1], acc[2]); acc[3] = MF(a1f, whhf[kt][1], acc[3]);
          acc[6] = MF(a0, whhf[kt][2], acc[6]); acc[7] = MF(a1f, whhf[kt][2], acc[7]);
        }
      }

      // ---- per-half 4-wave reduction (one sync) ----
      if (kq >= 2) {
        #pragma unroll
        for (int f = 0; f < 8; ++f) rv[rbase + (kq - 2) * 512 + f * 64 + ln] = acc[f];
      } else if (kq == 0) {
        #pragma unroll
        for (int j = 0; j < 4; ++j) rv[rbase + 1024 + j * 64 + ln] = acc[2 * j + 1];
      } else {
        #pragma unroll
        for (int j = 0; j < 4; ++j) rv[rbase + 1280 + j * 64 + ln] = acc[2 * j];
      }
      __syncthreads();

      if (kq < 2) {
        v4f m0, m1, m2, m3;
        if (kq == 0) {
          m0 = acc[0]; m1 = acc[2]; m2 = acc[4]; m3 = acc[6];
          #pragma unroll
          for (int w = 0; w < 2; ++w) {
            m0 += rv[rbase + w * 512 + 0 * 64 + ln]; m1 += rv[rbase + w * 512 + 2 * 64 + ln];
            m2 += rv[rbase + w * 512 + 4 * 64 + ln]; m3 += rv[rbase + w * 512 + 6 * 64 + ln];
          }
          m0 += rv[rbase + 1280 + 0 * 64 + ln]; m1 += rv[rbase + 1280 + 1 * 64 + ln];
          m2 += rv[rbase + 1280 + 2 * 64 + ln]; m3 += rv[rbase + 1280 + 3 * 64 + ln];
        } else {
          m0 = acc[1]; m1 = acc[3]; m2 = acc[5]; m3 = acc[7];
          #pragma unroll
          for (int w = 0; w < 2; ++w) {
            m0 += rv[rbase + w * 512 + 1 * 64 + ln]; m1 += rv[rbase + w * 512 + 3 * 64 + ln];
            m2 += rv[rbase + w * 512 + 5 * 64 + ln]; m3 += rv[rbase + w * 512 + 7 * 64 + ln];
          }
          m0 += rv[rbase + 1024 + 0 * 64 + ln]; m1 += rv[rbase + 1024 + 1 * 64 + ln];
          m2 += rv[rbase + 1024 + 2 * 64 + ln]; m3 += rv[rbase + 1024 + 3 * 64 + ln];
        }
        #pragma unroll
        for (int r4 = 0; r4 < 4; ++r4) {
          float rg = sigm(m0[r4] + bir + bhr);
          float zg = sigm(m1[r4] + biz + bhz);
          float ng = tanhx(m2[r4] + bin + rg * (m3[r4] + bhn));
          float hprev = (r4 == 0 ? hp0 : r4 == 1 ? hp1 : r4 == 2 ? hp2 : hp3);
          float hn = (1.f - zg) * ng + zg * hprev;
          if (r4 == 0) hp0 = hn; else if (r4 == 1) hp1 = hn; else if (r4 == 2) hp2 = hn; else hp3 = hn;
          trpS[half * 512 + (kq * 16 + lq * 4 + r4) * 16 + l16] = f2b(hn);
        }
        if (ln < 32) {
          int off = half * 1024 + kq * 512 + (ln >> 1) * 32 + (ln & 1) * 16;
          v4u hv = *reinterpret_cast<const v4u*>(reinterpret_cast<const char*>(trpS) + off);
          u64 pa = hC + (u64)t * 131072 + (u64)(cb * 2048) + (u64)off;
          stp16(pa, hv);   // L2 copy (same-XCD fast path)
          stc16(pa, hv);   // L3 copy (cross-XCD + fallback)
        }
      }

      // ---- issue NEXT-step probe, then xe prefetch ----
      {
        const u64 pa2 = hC + (u64)t * 131072 + probe_off;
        if (!esc) asm volatile("global_load_dword %0, %1, off sc0" : "=v"(pr) : "v"(pa2));
        else      asm volatile("global_load_dword %0, %1, off sc0 sc1" : "=v"(pr) : "v"(pa2));
        const USH* a1n = a1b + (size_t)(t + 1 < T_ ? t + 1 : t) * E_;
        #pragma unroll
        for (int kt = 0; kt < 4; ++kt) {
          pf[kt * 2]     = *reinterpret_cast<const uint4*>(a1n + kt * 32);
          pf[kt * 2 + 1] = *reinterpret_cast<const uint4*>(a1n + 16 * (T_ * E_) + kt * 32);
        }
      }
    }
  } else if (role < 4) {
    // ================= emission role: 2 sub-units of 256 threads =================
    const int sub = tid >> 8, stid = tid & 255;
    const int wv = stid >> 6, ln = stid & 63, l16 = ln & 15, lq = ln >> 4;
    const int stream = (idx8 * 2 + (role - 2)) * 2 + sub;   // 0..127
    v8bf fcf[8][4];
    #pragma unroll
    for (int kt = 0; kt < 8; ++kt)
      #pragma unroll
      for (int nt = 0; nt < 4; ++nt) {
        const float* wp = fcw + (size_t)(nt * 16 + l16) * H_ + wv * 256 + kt * 32 + lq * 8;
        fcf[kt][nt] = pack8(*reinterpret_cast<const float4*>(wp),
                            *reinterpret_cast<const float4*>(wp + 4));
      }
    float bias[4];
    #pragma unroll
    for (int nt = 0; nt < 4; ++nt) bias[nt] = fcb[nt * 16 + l16];

    v4f* rvE = reinterpret_cast<v4f*>(redS) + sub * 768;
    for (int tile = stream; tile < 2048; tile += 128) {
      int t = tile >> 2, bq = tile & 3;
      const u64 ab = (u64)(uintptr_t)hsC + (u64)t * 131072 + (u64)(bq >> 1) * 65536
                   + (u64)((lq >> 1) * 1024 + ((bq & 1) * 16 + l16) * 32 + (lq & 1) * 16);
      v4u ha2[8];
      while (true) {
        #pragma unroll
        for (int kt = 0; kt < 8; ++kt) ha2[kt] = ldc16(ab + (u64)((wv * 8 + kt) * 2048));
        asm volatile("s_waitcnt vmcnt(0)" ::: "memory");
        __builtin_amdgcn_sched_barrier(0);
        bool bad = false;
        #pragma unroll
        for (int kt = 0; kt < 8; ++kt) {
          #pragma unroll
          for (int d = 0; d < 4; ++d) bad |= (ha2[kt][d] == 0xFFFFFFFFu);
        }
        if (__ballot(bad) == 0ull) break;
        __builtin_amdgcn_s_sleep(32);
      }
      v4f acc[4];
      #pragma unroll
      for (int nt = 0; nt < 4; ++nt) acc[nt] = z4;
      #pragma unroll
      for (int kt = 0; kt < 8; ++kt) {
        v8bf a = __builtin_bit_cast(v8bf, ha2[kt]);
        #pragma unroll
        for (int nt = 0; nt < 4; ++nt) acc[nt] = MF(a, fcf[kt][nt], acc[nt]);
      }
      __syncthreads();
      if (wv != 0) {
        #pragma unroll
        for (int nt = 0; nt < 4; ++nt) rvE[(wv - 1) * 256 + nt * 64 + ln] = acc[nt];
      }
      __syncthreads();
      if (wv == 0) {
        #pragma unroll
        for (int nt = 0; nt < 4; ++nt) {
          v4f s = acc[nt];
          #pragma unroll
          for (int w = 0; w < 3; ++w) s += rvE[w * 256 + nt * 64 + ln];
          int k = nt * 16 + l16;
          #pragma unroll
          for (int r = 0; r < 4; ++r) {
            int b = bq * 16 + lq * 4 + r;
            float val = s[r] + bias[nt];
            u32 vb; { union { float f; u32 u; } c; c.f = val; vb = c.u; }
            stdw((u64)(uintptr_t)em + ((((size_t)b * T_ + t) * 64) + k) * 4, vb);
          }
        }
      }
    }
  } else if (role == 4 && idx8 < 8) {
    // ================= CRF role: 8 waves = 8 batch elements =================
    const int wv = tid >> 6, ln = tid & 63;
    float* trsS = redS;                         // 16KB
    int* tgS = (int*)(redS + 4096);             // 16KB
    for (int i = tid; i < 4096; i += 512) trsS[i] = trn[i];
    const int b = idx8 * 8 + wv;
    for (int i = ln; i < T_; i += 64) tgS[wv * 512 + i] = tags[b * T_ + i];
    __syncthreads();
    const int j = ln;
    const float stj = stv[j], enj = env[j];
    const u64 emb0 = (u64)(uintptr_t)em + ((size_t)b * T_) * 256 + (size_t)j * 4;
    float alpha = 0.f, num = 0.f; int tprev = 0;
    for (int t = 0; t < T_; ++t) {
      u32 ev;
      const u64 ea = emb0 + (size_t)t * 256;
      while (true) {
        asm volatile("global_load_dword %0, %1, off sc0 sc1" : "=v"(ev) : "v"(ea));
        asm volatile("s_waitcnt vmcnt(0)" ::: "memory");
        __builtin_amdgcn_sched_barrier(0);
        if (__ballot(ev == 0xFFFFFFFFu) == 0ull) break;
        __builtin_amdgcn_s_sleep(16);
      }
      float e; { union { u32 u; float f; } c; c.u = ev; e = c.f; }
      int ct = tgS[wv * 512 + t];
      float esh = __shfl(e, ct, 64);
      if (t == 0) {
        alpha = stj + e;
        num = stv[ct] + esh;
      } else {
        num += trsS[tprev * 64 + ct] + esh;
        float vv[64];
        #pragma unroll
        for (int i = 0; i < 64; ++i) vv[i] = __shfl(alpha, i, 64) + trsS[i * 64 + j];
        float mc[4];
        #pragma unroll
        for (int c4 = 0; c4 < 4; ++c4) {
          mc[c4] = vv[c4 * 16];
          #pragma unroll
          for (int ii = 1; ii < 16; ++ii) mc[c4] = fmaxf(mc[c4], vv[c4 * 16 + ii]);
        }
        float M = fmaxf(fmaxf(mc[0], mc[1]), fmaxf(mc[2], mc[3]));
        float sc[4] = {0.f, 0.f, 0.f, 0.f};
        #pragma unroll
        for (int c4 = 0; c4 < 4; ++c4)
          #pragma unroll
          for (int ii = 0; ii < 16; ++ii) sc[c4] += __expf(vv[c4 * 16 + ii] - M);
        alpha = M + __logf((sc[0] + sc[1]) + (sc[2] + sc[3])) + e;
      }
      tprev = ct;
    }
    num += env[tprev];                           // end_trans[tags[-1]]
    float v = alpha + enj;
    float mm = v;
    #pragma unroll
    for (int o = 32; o; o >>= 1) mm = fmaxf(mm, __shfl_xor(mm, o, 64));
    float ss = __expf(v - mm);
    #pragma unroll
    for (int o = 32; o; o >>= 1) ss += __shfl_xor(ss, o, 64);
    if (j == 0) {
      float r = (mm + __logf(ss)) - num;
      u32 rb; { union { float f; u32 u; } c; c.f = r; rb = c.u; }
      stdw((u64)(uintptr_t)res + (size_t)b * 4, rb);
    }
  } else if (blockIdx.x == 68) {
    // ================= final-sum role =================
    if (tid < 64) {
      u32 rb;
      const u64 ra = (u64)(uintptr_t)res + (size_t)tid * 4;
      while (true) {
        asm volatile("global_load_dword %0, %1, off sc0 sc1" : "=v"(rb) : "v"(ra));
        asm volatile("s_waitcnt vmcnt(0)" ::: "memory");
        __builtin_amdgcn_sched_barrier(0);
        if (__ballot(rb == 0xFFFFFFFFu) == 0ull) break;
        __builtin_amdgcn_s_sleep(32);
      }
      float v; { union { u32 u; float f; } c; c.u = rb; v = c.f; }
      #pragma unroll
      for (int o = 32; o; o >>= 1) v += __shfl_xor(v, o, 64);
      if (tid == 0) outp[0] = v;
    }
  }
}

extern "C" void kernel_launch(void* const* d_in, const int* in_sizes, int n_in,
                              void* d_out, int out_size, void* d_ws, size_t ws_size,
                              hipStream_t stream) {
  (void)in_sizes; (void)n_in; (void)out_size;
  const int*   x    = (const int*)d_in[0];
  const int*   tags = (const int*)d_in[1];
  const float* emb  = (const float*)d_in[2];
  const float* wih  = (const float*)d_in[3];
  const float* whh  = (const float*)d_in[4];
  const float* bih  = (const float*)d_in[5];
  const float* bhh  = (const float*)d_in[6];
  const float* fcw  = (const float*)d_in[7];
  const float* fcb  = (const float*)d_in[8];
  const float* str  = (const float*)d_in[9];
  const float* enr  = (const float*)d_in[10];
  const float* trn  = (const float*)d_in[11];

  char* ws = (char*)d_ws;
  char*  hsC  = ws;                        // 67,108,864: [t][group][cb][half][row][col] (0xFF)
  float* em   = (float*)(ws + 67108864);   //  8,388,608 (0xFF = NaN sentinel)
  float* res  = (float*)(ws + 75497472);   //        256 (0xFF sentinel)
  USH*   xeb  = (USH*)(ws + 75497728);     // 33,554,432
  if (ws_size < 109052160ull) return;

  hipMemsetAsync(ws, 0xFF, 75497728ull, stream);

  gatherk<<<B_ * T_, 128, 0, stream>>>(x, emb, xeb);
  fused<<<GRID, 512, 0, stream>>>(xeb, wih, whh, bih, bhh, hsC, fcw, fcb,
                                  em, tags, str, enr, trn, res, (float*)d_out);
}

// Round 13
// 2151.450 us; speedup vs baseline: 4.2504x; 4.2504x over previous
//
#include <hip/hip_runtime.h>

typedef unsigned short USH;
typedef unsigned int u32;
typedef unsigned long long u64;
typedef float v4f __attribute__((ext_vector_type(4)));
typedef __bf16 v8bf __attribute__((ext_vector_type(8)));
typedef u32 v4u __attribute__((ext_vector_type(4)));

#define B_ 64
#define T_ 512
#define E_ 512
#define H_ 1024
#define NSCAN 128
#define EMIT0 128
#define NEMIT 111
#define CRF0  239
#define FINB  255

__device__ __forceinline__ USH f2b(float x) {
  union { float f; u32 u; } v; v.f = x;
  u32 r = v.u + 0x7FFFu + ((v.u >> 16) & 1u);
  return (USH)(r >> 16);
}
__device__ __forceinline__ v8bf pack8(float4 a, float4 b) {
  union { USH s[8]; v8bf v; } r;
  r.s[0] = f2b(a.x); r.s[1] = f2b(a.y); r.s[2] = f2b(a.z); r.s[3] = f2b(a.w);
  r.s[4] = f2b(b.x); r.s[5] = f2b(b.y); r.s[6] = f2b(b.z); r.s[7] = f2b(b.w);
  return r.v;
}
__device__ __forceinline__ v4f MF(v8bf a, v8bf b, v4f c) {
  return __builtin_amdgcn_mfma_f32_16x16x32_bf16(a, b, c, 0, 0, 0);
}
__device__ __forceinline__ float sigm(float x) { return 1.0f / (1.0f + __expf(-x)); }
__device__ __forceinline__ float tanhx(float x) { return 1.0f - 2.0f / (__expf(2.0f * x) + 1.0f); }

// fully-coherent ops (bypass L1+L2): fresh from the L3 coherence point
__device__ __forceinline__ v4u ldc16(u64 a) {
  v4u d;
  asm volatile("global_load_dwordx4 %0, %1, off sc0 sc1" : "=v"(d) : "v"(a));
  return d;
}
__device__ __forceinline__ void stc16(u64 a, v4u d) {
  asm volatile("global_store_dwordx4 %0, %1, off sc1" :: "v"(a), "v"(d) : "memory");
}
__device__ __forceinline__ void stdw(u64 a, u32 v) {
  asm volatile("global_store_dword %0, %1, off sc1" :: "v"(a), "v"(v) : "memory");
}

// ---------------- embedding gather (-> bf16) ----------------
__global__ void gatherk(const int* __restrict__ x, const float* __restrict__ emb, USH* __restrict__ xeb) {
  int r = blockIdx.x;                       // r = b*T + t
  int id = x[r];
  const float4* e = reinterpret_cast<const float4*>(emb + (long)id * E_);
  float4 v = e[threadIdx.x];                // 128 threads * 4 floats = 512
  ushort4 q = make_ushort4(f2b(v.x), f2b(v.y), f2b(v.z), f2b(v.w));
  *reinterpret_cast<ushort4*>(xeb + (long)r * E_ + threadIdx.x * 4) = q;
}

// ---------------- fused persistent kernel ----------------
// blocks 0..127   : GRU scan (bg = blk>>6, cb = blk&63 -> 16 h-cols). Weights cast
//                   f32->bf16 into REGISTERS inline. Per-step tile hsC[t][bg][cb]
//                   (sentinel 0xFF). Sync: r9 probe mechanism with FUSED retry rounds:
//                   each retry issues probe THEN payload concurrently; when the probe
//                   reads non-sentinel the co-fetched payload is normally post-store
//                   too (sentinel-verified; dirty lines cost one extra round).
// blocks 128..238 : emissions (em, sc1 stores; em sentinel = 0xFFFFFFFF NaN).
// blocks 239..254 : CRF forward per batch element (polls em), writes res (sc1).
// block 255       : final sum of res -> d_out.
__global__ __launch_bounds__(256, 1) void fused(
    const USH* __restrict__ xeb, const float* __restrict__ wih, const float* __restrict__ whh,
    const float* __restrict__ bih, const float* __restrict__ bhh, char* __restrict__ hsC,
    const float* __restrict__ fcw, const float* __restrict__ fcb,
    float* __restrict__ em, const int* __restrict__ tags, const float* __restrict__ stv,
    const float* __restrict__ env, const float* __restrict__ trn, float* __restrict__ res,
    float* __restrict__ outp)
{
  __shared__ float redS[6144];   // 24KB: scan reduction / emission reduction / crf trs+tags
  __shared__ USH  trpS[512];     // 1KB h transpose

  const int tid = threadIdx.x;
  const int wv = tid >> 6, ln = tid & 63;
  const int l16 = ln & 15, lq = ln >> 4;
  const v4f z4 = {0.f, 0.f, 0.f, 0.f};

  if (blockIdx.x < NSCAN) {
    // ================= scan role =================
    const int bg = blockIdx.x >> 6, cb = blockIdx.x & 63;
    const int b0 = bg * 32, c0 = cb * 16;

    // weights f32 -> bf16 registers (one-time)
    v8bf wihf[4][3], whhf[8][3];
    #pragma unroll
    for (int kt = 0; kt < 4; ++kt)
      #pragma unroll
      for (int g = 0; g < 3; ++g) {
        const float* wp = wih + (size_t)(g * H_ + c0 + l16) * E_ + (wv * 16 + kt * 4 + lq) * 8;
        wihf[kt][g] = pack8(*reinterpret_cast<const float4*>(wp),
                            *reinterpret_cast<const float4*>(wp + 4));
      }
    #pragma unroll
    for (int kt = 0; kt < 8; ++kt)
      #pragma unroll
      for (int g = 0; g < 3; ++g) {
        const float* wp = whh + (size_t)(g * H_ + c0 + l16) * H_ + (wv * 32 + kt * 4 + lq) * 8;
        whhf[kt][g] = pack8(*reinterpret_cast<const float4*>(wp),
                            *reinterpret_cast<const float4*>(wp + 4));
      }

    const int cgl = c0 + l16;
    const float bir = bih[cgl], biz = bih[H_ + cgl], bin = bih[2 * H_ + cgl];
    const float bhr = bhh[cgl], bhz = bhh[H_ + cgl], bhn = bhh[2 * H_ + cgl];

    const USH* a1b = xeb + (size_t)(b0 + l16) * (T_ * E_) + wv * 128 + 8 * lq;
    const u64 hC = (u64)(uintptr_t)hsC + (u64)bg * 65536;
    const int lane_off = (wv * 16 + (lq >> 1)) * 1024 + l16 * 32 + (lq & 1) * 16;
    const u64 probe_off = (u64)((wv * 16 + l16) * 1024 + 1020);  // last dword of tile

    float hp0 = 0.f, hp1 = 0.f, hp2 = 0.f, hp3 = 0.f;
    v4f* rv = reinterpret_cast<v4f*>(redS);

    // prefetch xe for t=0
    uint4 pf[8];
    #pragma unroll
    for (int kt = 0; kt < 4; ++kt) {
      pf[kt * 2]     = *reinterpret_cast<const uint4*>(a1b + kt * 32);
      pf[kt * 2 + 1] = *reinterpret_cast<const uint4*>(a1b + 16 * (T_ * E_) + kt * 32);
    }
    u32 pr = 0;

    for (int t = 0; t < T_; ++t) {
      v4f acc[8];  // 0/1:R(m0,m1) 2/3:Z 4/5:NI 6/7:NH
      #pragma unroll
      for (int i = 0; i < 8; ++i) acc[i] = z4;

      // ---- phase 1: xe_t @ w_ih^T (regs only) ----
      #pragma unroll
      for (int kt = 0; kt < 4; ++kt) {
        v8bf a0 = __builtin_bit_cast(v8bf, pf[kt * 2]);
        v8bf a1f = __builtin_bit_cast(v8bf, pf[kt * 2 + 1]);
        acc[0] = MF(a0, wihf[kt][0], acc[0]); acc[1] = MF(a1f, wihf[kt][0], acc[1]);
        acc[2] = MF(a0, wihf[kt][1], acc[2]); acc[3] = MF(a1f, wihf[kt][1], acc[3]);
        acc[4] = MF(a0, wihf[kt][2], acc[4]); acc[5] = MF(a1f, wihf[kt][2], acc[5]);
      }

      if (t > 0) {
        const u64 hbase = hC + (u64)(t - 1) * 131072;
        v4u ha[16];
        bool have = false;   // payload co-issued in the last probe round?
        // ---- fused probe+payload rounds ----
        while (true) {
          asm volatile("s_waitcnt vmcnt(0)" ::: "memory");
          __builtin_amdgcn_sched_barrier(0);
          if (__ballot(pr != 0xFFFFFFFFu) == ~0ull) break;
          // probe first (earliest fetch), then payload — all in flight together
          asm volatile("global_load_dword %0, %1, off sc0 sc1" : "=v"(pr) : "v"(hbase + probe_off));
          #pragma unroll
          for (int kt = 0; kt < 8; ++kt) {
            ha[kt * 2]     = ldc16(hbase + lane_off + kt * 2048);
            ha[kt * 2 + 1] = ldc16(hbase + lane_off + kt * 2048 + 512);
          }
          have = true;
        }
        // ---- verify payload (issue fresh if never co-issued or dirty) ----
        while (true) {
          if (!have) {
            #pragma unroll
            for (int kt = 0; kt < 8; ++kt) {
              ha[kt * 2]     = ldc16(hbase + lane_off + kt * 2048);
              ha[kt * 2 + 1] = ldc16(hbase + lane_off + kt * 2048 + 512);
            }
            asm volatile("s_waitcnt vmcnt(0)" ::: "memory");
            __builtin_amdgcn_sched_barrier(0);
          }
          bool bad = false;
          #pragma unroll
          for (int f = 0; f < 16; ++f) {
            #pragma unroll
            for (int d = 0; d < 4; ++d) bad |= (ha[f][d] == 0xFFFFFFFFu);
          }
          if (__ballot(bad) == 0ull) break;
          have = false;
          __builtin_amdgcn_s_sleep(1);
        }
        // ---- phase 2: h_{t-1} @ w_hh^T ----
        #pragma unroll
        for (int kt = 0; kt < 8; ++kt) {
          v8bf a0 = __builtin_bit_cast(v8bf, ha[kt * 2]);
          v8bf a1f = __builtin_bit_cast(v8bf, ha[kt * 2 + 1]);
          acc[0] = MF(a0, whhf[kt][0], acc[0]); acc[1] = MF(a1f, whhf[kt][0], acc[1]);
          acc[2] = MF(a0, whhf[kt][1], acc[2]); acc[3] = MF(a1f, whhf[kt][1], acc[3]);
          acc[6] = MF(a0, whhf[kt][2], acc[6]); acc[7] = MF(a1f, whhf[kt][2], acc[7]);
        }
      }

      // ---- single-round cross-wave reduction (24KB), 1 sync ----
      if (wv >= 2) {
        #pragma unroll
        for (int f = 0; f < 8; ++f) rv[(wv - 2) * 512 + f * 64 + ln] = acc[f];
      } else if (wv == 0) {
        #pragma unroll
        for (int j = 0; j < 4; ++j) rv[1024 + j * 64 + ln] = acc[2 * j + 1];
      } else {
        #pragma unroll
        for (int j = 0; j < 4; ++j) rv[1280 + j * 64 + ln] = acc[2 * j];
      }
      __syncthreads();

      if (wv < 2) {
        v4f m0, m1, m2, m3;
        if (wv == 0) {
          m0 = acc[0]; m1 = acc[2]; m2 = acc[4]; m3 = acc[6];
          #pragma unroll
          for (int w = 0; w < 2; ++w) {
            m0 += rv[w * 512 + 0 * 64 + ln]; m1 += rv[w * 512 + 2 * 64 + ln];
            m2 += rv[w * 512 + 4 * 64 + ln]; m3 += rv[w * 512 + 6 * 64 + ln];
          }
          m0 += rv[1280 + 0 * 64 + ln]; m1 += rv[1280 + 1 * 64 + ln];
          m2 += rv[1280 + 2 * 64 + ln]; m3 += rv[1280 + 3 * 64 + ln];
        } else {
          m0 = acc[1]; m1 = acc[3]; m2 = acc[5]; m3 = acc[7];
          #pragma unroll
          for (int w = 0; w < 2; ++w) {
            m0 += rv[w * 512 + 1 * 64 + ln]; m1 += rv[w * 512 + 3 * 64 + ln];
            m2 += rv[w * 512 + 5 * 64 + ln]; m3 += rv[w * 512 + 7 * 64 + ln];
          }
          m0 += rv[1024 + 0 * 64 + ln]; m1 += rv[1024 + 1 * 64 + ln];
          m2 += rv[1024 + 2 * 64 + ln]; m3 += rv[1024 + 3 * 64 + ln];
        }
        #pragma unroll
        for (int r4 = 0; r4 < 4; ++r4) {
          float rg = sigm(m0[r4] + bir + bhr);
          float zg = sigm(m1[r4] + biz + bhz);
          float ng = tanhx(m2[r4] + bin + rg * (m3[r4] + bhn));
          float hprev = (r4 == 0 ? hp0 : r4 == 1 ? hp1 : r4 == 2 ? hp2 : hp3);
          float hn = (1.f - zg) * ng + zg * hprev;
          if (r4 == 0) hp0 = hn; else if (r4 == 1) hp1 = hn; else if (r4 == 2) hp2 = hn; else hp3 = hn;
          trpS[(wv * 16 + lq * 4 + r4) * 16 + l16] = f2b(hn);
        }
        if (ln < 32) {
          v4u hv = *reinterpret_cast<const v4u*>(trpS + wv * 256 + ln * 8);
          stc16(hC + (u64)t * 131072 + (u64)cb * 1024 + (u64)(wv * 512) + (u64)ln * 16, hv);
        }
      }

      // ---- issue NEXT-step probe (h_t readiness), then xe prefetch ----
      {
        const u64 hb = hC + (u64)t * 131072;
        asm volatile("global_load_dword %0, %1, off sc0 sc1" : "=v"(pr) : "v"(hb + probe_off));
        const USH* a1n = a1b + (size_t)(t + 1 < T_ ? t + 1 : t) * E_;
        #pragma unroll
        for (int kt = 0; kt < 4; ++kt) {
          pf[kt * 2]     = *reinterpret_cast<const uint4*>(a1n + kt * 32);
          pf[kt * 2 + 1] = *reinterpret_cast<const uint4*>(a1n + 16 * (T_ * E_) + kt * 32);
        }
      }
    }
  } else if (blockIdx.x < CRF0) {
    // ================= emission role =================
    const int e = blockIdx.x - EMIT0;
    v8bf fcf[8][4];
    #pragma unroll
    for (int kt = 0; kt < 8; ++kt)
      #pragma unroll
      for (int nt = 0; nt < 4; ++nt) {
        const float* wp = fcw + (size_t)(nt * 16 + l16) * H_ + wv * 256 + kt * 32 + lq * 8;
        fcf[kt][nt] = pack8(*reinterpret_cast<const float4*>(wp),
                            *reinterpret_cast<const float4*>(wp + 4));
      }
    float bias[4];
    #pragma unroll
    for (int nt = 0; nt < 4; ++nt) bias[nt] = fcb[nt * 16 + l16];

    v4f* rvE = reinterpret_cast<v4f*>(redS);
    for (int tile = e; tile < 2048; tile += NEMIT) {
      int t = tile >> 2, bq = tile & 3;
      const u64 ab = (u64)(uintptr_t)hsC + (u64)t * 131072 + (u64)(bq >> 1) * 65536
                   + (u64)((bq & 1) * 16 + l16) * 32 + (u64)(wv * 16 + (lq >> 1)) * 1024 + (u64)(lq & 1) * 16;
      v4u ha2[8];
      while (true) {
        #pragma unroll
        for (int kt = 0; kt < 8; ++kt) ha2[kt] = ldc16(ab + kt * 2048);
        asm volatile("s_waitcnt vmcnt(0)" ::: "memory");
        __builtin_amdgcn_sched_barrier(0);
        bool bad = false;
        #pragma unroll
        for (int kt = 0; kt < 8; ++kt) {
          #pragma unroll
          for (int d = 0; d < 4; ++d) bad |= (ha2[kt][d] == 0xFFFFFFFFu);
        }
        if (__ballot(bad) == 0ull) break;
        __builtin_amdgcn_s_sleep(32);
      }
      v4f acc[4];
      #pragma unroll
      for (int nt = 0; nt < 4; ++nt) acc[nt] = z4;
      #pragma unroll
      for (int kt = 0; kt < 8; ++kt) {
        v8bf a = __builtin_bit_cast(v8bf, ha2[kt]);
        #pragma unroll
        for (int nt = 0; nt < 4; ++nt) acc[nt] = MF(a, fcf[kt][nt], acc[nt]);
      }
      __syncthreads();
      if (wv != 0) {
        #pragma unroll
        for (int nt = 0; nt < 4; ++nt) rvE[(wv - 1) * 256 + nt * 64 + ln] = acc[nt];
      }
      __syncthreads();
      if (wv == 0) {
        #pragma unroll
        for (int nt = 0; nt < 4; ++nt) {
          v4f s = acc[nt];
          #pragma unroll
          for (int w = 0; w < 3; ++w) s += rvE[w * 256 + nt * 64 + ln];
          int k = nt * 16 + l16;
          #pragma unroll
          for (int r = 0; r < 4; ++r) {
            int b = bq * 16 + lq * 4 + r;
            float val = s[r] + bias[nt];
            u32 vb; { union { float f; u32 u; } c; c.f = val; vb = c.u; }
            stdw((u64)(uintptr_t)em + ((((size_t)b * T_ + t) * 64) + k) * 4, vb);
          }
        }
      }
    }
  } else if (blockIdx.x < FINB) {
    // ================= CRF role: wave wv handles batch b =================
    float* trsS = redS;                         // [4096] = 16KB
    int* tgS = (int*)(redS + 4096);             // [4][512] = 8KB
    for (int i = tid; i < 4096; i += 256) trsS[i] = trn[i];
    const int b = (blockIdx.x - CRF0) * 4 + wv;
    for (int i = ln; i < T_; i += 64) tgS[wv * 512 + i] = tags[b * T_ + i];
    __syncthreads();
    const int j = ln;
    const float stj = stv[j], enj = env[j];
    const u64 emb0 = (u64)(uintptr_t)em + ((size_t)b * T_) * 256 + (size_t)j * 4;
    float alpha = 0.f, num = 0.f; int tprev = 0;
    for (int t = 0; t < T_; ++t) {
      u32 ev;
      const u64 ea = emb0 + (size_t)t * 256;
      while (true) {
        asm volatile("global_load_dword %0, %1, off sc0 sc1" : "=v"(ev) : "v"(ea));
        asm volatile("s_waitcnt vmcnt(0)" ::: "memory");
        __builtin_amdgcn_sched_barrier(0);
        if (__ballot(ev == 0xFFFFFFFFu) == 0ull) break;
        __builtin_amdgcn_s_sleep(16);
      }
      float e; { union { u32 u; float f; } c; c.u = ev; e = c.f; }
      int ct = tgS[wv * 512 + t];
      float esh = __shfl(e, ct, 64);
      if (t == 0) {
        alpha = stj + e;
        num = stv[ct] + esh;
      } else {
        num += trsS[tprev * 64 + ct] + esh;
        float vv[64];
        #pragma unroll
        for (int i = 0; i < 64; ++i) vv[i] = __shfl(alpha, i, 64) + trsS[i * 64 + j];
        float mc[4];
        #pragma unroll
        for (int c4 = 0; c4 < 4; ++c4) {
          mc[c4] = vv[c4 * 16];
          #pragma unroll
          for (int ii = 1; ii < 16; ++ii) mc[c4] = fmaxf(mc[c4], vv[c4 * 16 + ii]);
        }
        float M = fmaxf(fmaxf(mc[0], mc[1]), fmaxf(mc[2], mc[3]));
        float sc[4] = {0.f, 0.f, 0.f, 0.f};
        #pragma unroll
        for (int c4 = 0; c4 < 4; ++c4)
          #pragma unroll
          for (int ii = 0; ii < 16; ++ii) sc[c4] += __expf(vv[c4 * 16 + ii] - M);
        alpha = M + __logf((sc[0] + sc[1]) + (sc[2] + sc[3])) + e;
      }
      tprev = ct;
    }
    num += env[tprev];                           // end_trans[tags[-1]]
    float v = alpha + enj;
    float mm = v;
    #pragma unroll
    for (int o = 32; o; o >>= 1) mm = fmaxf(mm, __shfl_xor(mm, o, 64));
    float ss = __expf(v - mm);
    #pragma unroll
    for (int o = 32; o; o >>= 1) ss += __shfl_xor(ss, o, 64);
    if (j == 0) {
      float r = (mm + __logf(ss)) - num;
      u32 rb; { union { float f; u32 u; } c; c.f = r; rb = c.u; }
      stdw((u64)(uintptr_t)res + (size_t)b * 4, rb);
    }
  } else {
    // ================= final-sum role =================
    if (tid < 64) {
      u32 rb;
      const u64 ra = (u64)(uintptr_t)res + (size_t)tid * 4;
      while (true) {
        asm volatile("global_load_dword %0, %1, off sc0 sc1" : "=v"(rb) : "v"(ra));
        asm volatile("s_waitcnt vmcnt(0)" ::: "memory");
        __builtin_amdgcn_sched_barrier(0);
        if (__ballot(rb == 0xFFFFFFFFu) == 0ull) break;
        __builtin_amdgcn_s_sleep(32);
      }
      float v; { union { u32 u; float f; } c; c.u = rb; v = c.f; }
      #pragma unroll
      for (int o = 32; o; o >>= 1) v += __shfl_xor(v, o, 64);
      if (tid == 0) outp[0] = v;
    }
  }
}

extern "C" void kernel_launch(void* const* d_in, const int* in_sizes, int n_in,
                              void* d_out, int out_size, void* d_ws, size_t ws_size,
                              hipStream_t stream) {
  (void)in_sizes; (void)n_in; (void)out_size;
  const int*   x    = (const int*)d_in[0];
  const int*   tags = (const int*)d_in[1];
  const float* emb  = (const float*)d_in[2];
  const float* wih  = (const float*)d_in[3];
  const float* whh  = (const float*)d_in[4];
  const float* bih  = (const float*)d_in[5];
  const float* bhh  = (const float*)d_in[6];
  const float* fcw  = (const float*)d_in[7];
  const float* fcb  = (const float*)d_in[8];
  const float* str  = (const float*)d_in[9];
  const float* enr  = (const float*)d_in[10];
  const float* trn  = (const float*)d_in[11];

  char* ws = (char*)d_ws;
  // workspace layout (bytes)
  char*  hsC  = ws;                        // 67,108,864: [t][group][cb][row][col] h stream (0xFF)
  float* em   = (float*)(ws + 67108864);   //  8,388,608: [B][T][64] f32 (0xFF = NaN sentinel)
  float* res  = (float*)(ws + 75497472);   //        256 (0xFF sentinel)
  USH*   xeb  = (USH*)(ws + 75497728);     // 33,554,432
  if (ws_size < 109052160ull) return;

  // sentinel fills (every call / every replay): hsC + em + res in one memset
  hipMemsetAsync(ws, 0xFF, 75497728ull, stream);

  gatherk<<<B_ * T_, 128, 0, stream>>>(x, emb, xeb);
  fused<<<256, 256, 0, stream>>>(xeb, wih, whh, bih, bhh, hsC, fcw, fcb,
                                 em, tags, str, enr, trn, res, (float*)d_out);
}